// Round 11
// baseline (126.466 us; speedup 1.0000x reference)
//
#include <hip/hip_runtime.h>

typedef __attribute__((ext_vector_type(8))) short s16x8;
typedef __attribute__((ext_vector_type(4))) short s16x4;
typedef __attribute__((ext_vector_type(4))) float f32x4;
typedef __attribute__((ext_vector_type(4))) unsigned int u32x4;
typedef __attribute__((ext_vector_type(2))) unsigned int u32x2;
typedef unsigned short u16;
typedef unsigned int u32;

#define LOG2E 1.4426950408889634f

__device__ __forceinline__ u16 f2bf(float x) {
  u32 u = __float_as_uint(x);
  u += 0x7FFFu + ((u >> 16) & 1u);
  return (u16)(u >> 16);
}

__device__ __forceinline__ float bf2f(u16 x) {
  return __uint_as_float((u32)x << 16);
}

// pack two f32 into bf16x2 (truncating) with a single v_perm_b32
__device__ __forceinline__ u32 pack_bf_trunc(float lo, float hi) {
  return __builtin_amdgcn_perm(__float_as_uint(hi), __float_as_uint(lo), 0x07060302u);
}

__device__ __forceinline__ void gl_lds16(const void* g, void* l) {
  __builtin_amdgcn_global_load_lds((const __attribute__((address_space(1))) void*)g,
                                   (__attribute__((address_space(3))) void*)l, 16, 0, 0);
}

#define MFMA16(a, b, c) __builtin_amdgcn_mfma_f32_16x16x32_bf16((a), (b), (c), 0, 0, 0)

// ---------------- fused prep kernel ----------------

__global__ __launch_bounds__(256) void prep(const float* __restrict__ hs,
                                            const float* __restrict__ Wq,
                                            const float* __restrict__ Wk,
                                            const float* __restrict__ Wv,
                                            const float* __restrict__ Wo,
                                            const float* __restrict__ tbl,
                                            u16* __restrict__ hsb,
                                            u16* __restrict__ wt,
                                            u16* __restrict__ wot,
                                            float* __restrict__ biasT) {
  const int blk = blockIdx.x;
  const int tid = threadIdx.x;
  if (blk < 2048) {
    const int i = blk * 256 + tid;
    const float4* s4 = (const float4*)hs;
    float4 a = s4[i * 2];
    float4 b = s4[i * 2 + 1];
    s16x8 o;
    o[0] = (short)f2bf(a.x); o[1] = (short)f2bf(a.y);
    o[2] = (short)f2bf(a.z); o[3] = (short)f2bf(a.w);
    o[4] = (short)f2bf(b.x); o[5] = (short)f2bf(b.y);
    o[6] = (short)f2bf(b.z); o[7] = (short)f2bf(b.w);
    *(s16x8*)&hsb[i * 8] = o;
  } else if (blk < 4096) {
    int r = blk - 2048;
    const int sel = r >> 9;
    r &= 511;
    const float* W = sel == 0 ? Wq : (sel == 1 ? Wk : (sel == 2 ? Wv : Wo));
    u16* dst = sel == 3 ? wot : wt + sel * 1048576;
    const int n = (r & 15) * 64 + (tid & 63);
    const int kb = (r >> 4) * 32 + (tid >> 6) * 8;
    s16x8 o;
#pragma unroll
    for (int j = 0; j < 8; ++j) o[j] = (short)f2bf(W[(kb + j) * 1024 + n]);
    *(s16x8*)&dst[n * 1024 + kb] = o;
  } else {
    const int i = (blk - 4096) * 256 + tid;
    const int h = i >> 12, dp = i & 4095;
    const int delta = dp - 2047;
    const int rp = delta < 0 ? -delta : delta;
    int bucket = delta > 0 ? 16 : 0;
    if (rp < 8)
      bucket += rp;
    else
      bucket += 8 + (rp >= 12) + (rp >= 16) + (rp >= 23) + (rp >= 32) +
                (rp >= 46) + (rp >= 64) + (rp >= 91);
    biasT[i] = tbl[bucket * 16 + h] * LOG2E;
  }
}

// ---------------- GEMM core v2: 2-phase double-buffered, 128x128 ----------------

__device__ __forceinline__ void gemm_core(const u16* __restrict__ A,
                                          const u16* __restrict__ Bt,
                                          int m0, int n0,
                                          u16* shbuf, f32x4 acc[4][4]) {
  const int tid = threadIdx.x;
  const int w = tid >> 6, l = tid & 63, g = l >> 4, m15 = l & 15;
  const int wr = (w >> 1) * 64, wc = (w & 1) * 64;
#pragma unroll
  for (int i = 0; i < 4; ++i)
#pragma unroll
    for (int j = 0; j < 4; ++j) acc[i][j] = (f32x4){0.f, 0.f, 0.f, 0.f};

#define GSTAGE(buf, k0)                                                    \
  {                                                                        \
    _Pragma("unroll") for (int c = 0; c < 2; ++c) {                        \
      const int idx = c * 256 + tid;                                       \
      const int row = idx >> 2, col4 = idx & 3;                            \
      const int scol = col4 ^ ((row >> 1) & 3);                            \
      gl_lds16(&A[(m0 + row) * 1024 + (k0) + scol * 8],                    \
               (char*)shbuf + (buf)*8192 + c * 4096 + w * 1024);           \
      gl_lds16(&Bt[(n0 + row) * 1024 + (k0) + scol * 8],                   \
               (char*)shbuf + 16384 + (buf)*8192 + c * 4096 + w * 1024);   \
    }                                                                      \
  }

  GSTAGE(0, 0);
  int cur = 0;
  for (int kt = 0; kt < 32; ++kt) {
    __syncthreads();  // drains vmcnt: buf[cur] ready; buf[cur^1] reads done
    if (kt < 31) GSTAGE(cur ^ 1, (kt + 1) * 32);
    const u16* Asb = shbuf + cur * 4096;
    const u16* Bsb = shbuf + 8192 + cur * 4096;
    s16x8 af[4], bfr[4];
#pragma unroll
    for (int mf = 0; mf < 4; ++mf) {
      const int row = wr + mf * 16 + m15;
      af[mf] = *(const s16x8*)&Asb[(row * 4 + (g ^ ((row >> 1) & 3))) * 8];
    }
#pragma unroll
    for (int nf = 0; nf < 4; ++nf) {
      const int row = wc + nf * 16 + m15;
      bfr[nf] = *(const s16x8*)&Bsb[(row * 4 + (g ^ ((row >> 1) & 3))) * 8];
    }
#pragma unroll
    for (int mf = 0; mf < 4; ++mf)
#pragma unroll
      for (int nf = 0; nf < 4; ++nf)
        acc[mf][nf] = MFMA16(af[mf], bfr[nf], acc[mf][nf]);
    cur ^= 1;
  }
#undef GSTAGE
}

// QKV: grid 768 blocks 1D, XCD-chunked (8m x 12n per XCD).
// Q/K row-major [4096][1024]; V transposed through LDS (coalesced) to
// VT[(b*16+h)*64 + d][2048].
__global__ __launch_bounds__(256) void gemm_qkv(const u16* __restrict__ X,
                                                const u16* __restrict__ Wt,
                                                u16* __restrict__ Q,
                                                u16* __restrict__ Kb,
                                                u16* __restrict__ VT) {
  __shared__ u16 shbuf[16384];  // 32 KB: dbuf A|B during GEMM, transpose tile after
  f32x4 acc[4][4];
  const int flat = blockIdx.x;
  const int x = flat & 7, i = flat >> 3;  // i in [0,96)
  const int m0 = ((x & 3) * 8 + (i & 7)) * 128;
  const int n0 = ((x >> 2) * 12 + (i >> 3)) * 128;
  gemm_core(X, Wt, m0, n0, shbuf, acc);

  const int tid = threadIdx.x;
  const int w = tid >> 6, l = tid & 63, g = l >> 4, m15 = l & 15;
  const int wr = (w >> 1) * 64, wc = (w & 1) * 64;
  const int nsel = n0 >> 10;
  const int ncol0 = (n0 & 1023) + wc;
  if (nsel == 2) {
    // V^T via LDS transpose then coalesced 16B stores along s.
    __syncthreads();
#pragma unroll
    for (int mf = 0; mf < 4; ++mf) {
      const int s_base = wr + mf * 16 + g * 4;
#pragma unroll
      for (int nf = 0; nf < 4; ++nf) {
        const int d_loc = wc + nf * 16 + m15;
        s16x4 pk;
#pragma unroll
        for (int r = 0; r < 4; ++r) pk[r] = (short)f2bf(acc[mf][nf][r]);
        *(s16x4*)&shbuf[d_loc * 128 + (s_base ^ ((d_loc & 7) << 3))] = pk;
      }
    }
    __syncthreads();
    const int b = m0 >> 11, sg0 = m0 & 2047;
#pragma unroll
    for (int it = 0; it < 8; ++it) {
      const int d_loc = it * 16 + w * 4 + g;
      const s16x8 v =
          *(const s16x8*)&shbuf[d_loc * 128 + ((m15 * 8) ^ ((d_loc & 7) << 3))];
      const int col = (n0 & 1023) + d_loc;
      *(s16x8*)&VT[((b * 16 + (col >> 6)) * 64 + (col & 63)) * 2048 + sg0 + m15 * 8] = v;
    }
  } else {
    u16* dst = nsel == 0 ? Q : Kb;
    const float scale = nsel == 0 ? 0.125f * LOG2E : 1.0f;
#pragma unroll
    for (int mf = 0; mf < 4; ++mf) {
      const int rbase = m0 + wr + mf * 16 + g * 4;
#pragma unroll
      for (int nf = 0; nf < 4; ++nf) {
        const int col = ncol0 + nf * 16 + m15;
#pragma unroll
        for (int r = 0; r < 4; ++r)
          dst[(rbase + r) * 1024 + col] = f2bf(acc[mf][nf][r] * scale);
      }
    }
  }
}

// ---------------- gemm_out v2: merge fused into A-staging ----------------
// 128x64 tiles, 512 blocks (2/CU). A = (po0+po1)*den merged in registers
// (T14 split: loads issued post-barrier, merged+ds_written post-compute).
// den = 1/(ls0+ls1) precomputed per block into an 8KB LDS table.
// B (Wot) keeps the global_load_lds path.

__global__ __launch_bounds__(256) void gemm_out(const u16* __restrict__ po0,
                                                const u16* __restrict__ po1,
                                                const float* __restrict__ pls,
                                                const u16* __restrict__ Wot,
                                                float* __restrict__ Out) {
  __shared__ u16 shbuf[12288];    // A dbuf 16KB | B dbuf 8KB
  __shared__ float denbuf[2048];  // [128 rows][16 heads]
  f32x4 acc[4][2];
  const int flat = blockIdx.x;
  const int x = flat & 7, i = flat >> 3;  // i in [0,64)
  const int m0 = ((x & 3) * 8 + (i & 7)) * 128;
  const int n0 = ((x >> 2) * 8 + (i >> 3)) * 64;

  const int tid = threadIdx.x;
  const int w = tid >> 6, l = tid & 63, g = l >> 4, m15 = l & 15;
  const int wr = (w >> 1) * 64, wc = (w & 1) * 32;
#pragma unroll
  for (int mf = 0; mf < 4; ++mf)
#pragma unroll
    for (int nf = 0; nf < 2; ++nf) acc[mf][nf] = (f32x4){0.f, 0.f, 0.f, 0.f};

  // merge denominators for this block's 128 rows x 16 heads (coalesced)
  for (int jj = tid; jj < 2048; jj += 256) {
    const int li = (m0 + (jj >> 4)) * 16 + (jj & 15);
    denbuf[jj] = 1.0f / (pls[li] + pls[65536 + li]);
  }

  // per-thread A staging coords (2 chunks of 8 elems)
  int arow[2], acol[2], adst[2];
#pragma unroll
  for (int c = 0; c < 2; ++c) {
    const int idx = c * 256 + tid;
    const int row = idx >> 2, col4 = idx & 3;
    arow[c] = row;
    acol[c] = (col4 ^ ((row >> 1) & 3)) * 8;  // swizzled source col (elems)
    adst[c] = (row * 4 + col4) * 8;           // LDS slot (elems)
  }

  s16x8 la[2], lb[2];

#define A_LOAD(k0)                                                         \
  {                                                                        \
    _Pragma("unroll") for (int c = 0; c < 2; ++c) {                        \
      const int off = (m0 + arow[c]) * 1024 + (k0) + acol[c];              \
      la[c] = *(const s16x8*)&po0[off];                                    \
      lb[c] = *(const s16x8*)&po1[off];                                    \
    }                                                                      \
  }

#define A_WRITE(buf, k0)                                                         \
  {                                                                              \
    _Pragma("unroll") for (int c = 0; c < 2; ++c) {                              \
      const float den = denbuf[arow[c] * 16 + (((k0) + acol[c]) >> 6)];          \
      u32 pk[4];                                                                 \
      _Pragma("unroll") for (int j = 0; j < 4; ++j) {                            \
        const float v0 =                                                         \
            (bf2f((u16)la[c][2 * j]) + bf2f((u16)lb[c][2 * j])) * den;           \
        const float v1 =                                                         \
            (bf2f((u16)la[c][2 * j + 1]) + bf2f((u16)lb[c][2 * j + 1])) * den;   \
        pk[j] = pack_bf_trunc(v0, v1);                                           \
      }                                                                          \
      *(u32x4*)&shbuf[(buf)*4096 + adst[c]] = (u32x4){pk[0], pk[1], pk[2], pk[3]}; \
    }                                                                            \
  }

#define B_STAGE(buf, k0)                                                   \
  {                                                                        \
    const int row = tid >> 2, col4 = tid & 3;                              \
    const int scol = col4 ^ ((row >> 1) & 3);                              \
    gl_lds16(&Wot[(n0 + row) * 1024 + (k0) + scol * 8],                    \
             (char*)shbuf + 16384 + (buf)*4096 + (w >> 1) * 2048 +         \
                 (tid & 127) * 16);                                        \
  }

  A_LOAD(0);
  B_STAGE(0, 0);
  __syncthreads();  // denbuf visible; B(0) drained
  A_WRITE(0, 0);

  int cur = 0;
  for (int kt = 0; kt < 32; ++kt) {
    __syncthreads();  // A-writes to buf[cur] visible; B buf[cur] ready
    if (kt < 31) {
      A_LOAD((kt + 1) * 32);      // latency hides under compute below
      B_STAGE(cur ^ 1, (kt + 1) * 32);
    }
    const u16* Asb = shbuf + cur * 4096;
    const u16* Bsb = shbuf + 8192 + cur * 2048;
    s16x8 af[4], bfr[2];
#pragma unroll
    for (int mf = 0; mf < 4; ++mf) {
      const int row = wr + mf * 16 + m15;
      af[mf] = *(const s16x8*)&Asb[(row * 4 + (g ^ ((row >> 1) & 3))) * 8];
    }
#pragma unroll
    for (int nf = 0; nf < 2; ++nf) {
      const int row = wc + nf * 16 + m15;
      bfr[nf] = *(const s16x8*)&Bsb[(row * 4 + (g ^ ((row >> 1) & 3))) * 8];
    }
#pragma unroll
    for (int mf = 0; mf < 4; ++mf)
#pragma unroll
      for (int nf = 0; nf < 2; ++nf)
        acc[mf][nf] = MFMA16(af[mf], bfr[nf], acc[mf][nf]);
    if (kt < 31) A_WRITE(cur ^ 1, (kt + 1) * 32);  // safe: all reads of buf^1 done pre-barrier
    cur ^= 1;
  }
#undef A_LOAD
#undef A_WRITE
#undef B_STAGE

#pragma unroll
  for (int mf = 0; mf < 4; ++mf) {
    const int rbase = m0 + wr + mf * 16 + g * 4;
#pragma unroll
    for (int nf = 0; nf < 2; ++nf) {
      const int col = n0 + wc + nf * 16 + m15;
#pragma unroll
      for (int r = 0; r < 4; ++r)
        Out[(rbase + r) * 1024 + col] = acc[mf][nf][r];
    }
  }
}

// ---------------- flash attention v5: KV-split x2 (proven config) ----------------

__global__ __launch_bounds__(256, 4) void attn_kernel(const u16* __restrict__ Qg,
                                                      const u16* __restrict__ Kg,
                                                      const u16* __restrict__ VTg,
                                                      const float* __restrict__ biasT,
                                                      const float* __restrict__ tbl,
                                                      u16* __restrict__ po0,
                                                      u16* __restrict__ po1,
                                                      float* __restrict__ pls) {
  __shared__ u16 KT[2][4096];   // [64 kv][64 kdim] swizzled, dbuf
  __shared__ u16 VTs[2][4096];  // [64 dv][64 kv]  swizzled, dbuf

  const int tid = threadIdx.x;
  const int w = tid >> 6, l = tid & 63, g = l >> 4, m15 = l & 15;
  const int flat = blockIdx.x;
  const int nf_ = (flat & 7) * 128 + (flat >> 3);
  const int bh = nf_ >> 5;
  const int rem = nf_ & 31;
  const int half = rem >> 4, qblk = rem & 15;
  const int b = bh >> 4, h = bh & 15;
  const int qw = qblk * 128 + w * 32;  // this wave's q base (32 rows)
  const int kvbase = half * 1024;

  u16* poh = half ? po1 : po0;
  float* plsh = pls + half * 65536;

  const float fpos = tbl[31 * 16 + h] * LOG2E;  // delta >= 91 bucket
  const float fneg = tbl[15 * 16 + h] * LOG2E;  // delta <= -91 bucket

  s16x8 aq[2][2];
#pragma unroll
  for (int qs = 0; qs < 2; ++qs) {
    const u16* qp = &Qg[(b * 2048 + qw + qs * 16 + m15) * 1024 + h * 64 + g * 8];
    aq[qs][0] = *(const s16x8*)qp;
    aq[qs][1] = *(const s16x8*)(qp + 32);
  }

  s16x8 vone;
#pragma unroll
  for (int j = 0; j < 8; ++j) vone[j] = (short)0x3F80;  // bf16 1.0

  f32x4 o[2][4];
  f32x4 ls4[2];
#pragma unroll
  for (int qs = 0; qs < 2; ++qs) {
    ls4[qs] = (f32x4){0.f, 0.f, 0.f, 0.f};
#pragma unroll
    for (int d = 0; d < 4; ++d) o[qs][d] = (f32x4){0.f, 0.f, 0.f, 0.f};
  }

  const u16* Kbase = &Kg[(b * 2048 + kvbase) * 1024 + h * 64];
  const u16* Vbase = &VTg[bh * 64 * 2048 + kvbase];

#define STAGE(buf, kv0)                                                          \
  {                                                                              \
    _Pragma("unroll") for (int c = 0; c < 2; ++c) {                              \
      const int idx = c * 256 + tid;                                             \
      const int row = idx >> 3, col16 = idx & 7;                                 \
      const int scol = col16 ^ (row & 7);                                        \
      gl_lds16(&Kbase[(kv0 + row) * 1024 + scol * 8],                            \
               (char*)KT + (buf)*8192 + c * 4096 + w * 1024);                    \
      gl_lds16(&Vbase[row * 2048 + (kv0) + scol * 8],                            \
               (char*)VTs + (buf)*8192 + c * 4096 + w * 1024);                   \
    }                                                                            \
  }

  STAGE(0, 0);
  int cur = 0;
  for (int t = 0; t < 16; ++t) {
    const int kv0 = t * 64;  // relative to kvbase
    __syncthreads();         // drains vmcnt: buf[cur] ready; buf[cur^1] free
    if (t < 15) STAGE(cur ^ 1, kv0 + 64);

    const u16* KTc = &KT[cur][0];
    const u16* VTc = &VTs[cur][0];

    f32x4 s[2][4];
    const int diff = kvbase + kv0 - qw;
    if (diff <= -160 || diff >= 128) {
      const float bc = diff > 0 ? fpos : fneg;
#pragma unroll
      for (int qs = 0; qs < 2; ++qs)
#pragma unroll
        for (int c = 0; c < 4; ++c) s[qs][c] = (f32x4){bc, bc, bc, bc};
    } else {
#pragma unroll
      for (int qs = 0; qs < 2; ++qs) {
        const float* bp =
            &biasT[h * 4096 + kvbase + kv0 + g * 4 - qw - qs * 16 - m15 + 2047];
#pragma unroll
        for (int c = 0; c < 4; ++c)
#pragma unroll
          for (int r = 0; r < 4; ++r) s[qs][c][r] = bp[c * 16 + r];
      }
    }

    __builtin_amdgcn_s_setprio(1);
#pragma unroll
    for (int ks = 0; ks < 2; ++ks) {
#pragma unroll
      for (int c = 0; c < 4; ++c) {
        const int row = c * 16 + m15;
        const s16x8 bk = *(const s16x8*)&KTc[(row * 8 + ((ks * 4 + g) ^ (row & 7))) * 8];
        s[0][c] = MFMA16(bk, aq[0][ks], s[0][c]);
        s[1][c] = MFMA16(bk, aq[1][ks], s[1][c]);
      }
    }
    __builtin_amdgcn_s_setprio(0);

    s16x8 pa[2][2];
#pragma unroll
    for (int qs = 0; qs < 2; ++qs) {
      u32 w01[4], w23[4];
#pragma unroll
      for (int c = 0; c < 4; ++c) {
        w01[c] = pack_bf_trunc(__builtin_amdgcn_exp2f(s[qs][c][0]),
                               __builtin_amdgcn_exp2f(s[qs][c][1]));
        w23[c] = pack_bf_trunc(__builtin_amdgcn_exp2f(s[qs][c][2]),
                               __builtin_amdgcn_exp2f(s[qs][c][3]));
      }
#pragma unroll
      for (int ks = 0; ks < 2; ++ks) {
        u32x2 rA = __builtin_amdgcn_permlane32_swap(w01[2 * ks], w01[2 * ks + 1], false, false);
        u32x2 rB = __builtin_amdgcn_permlane16_swap(rA[0], rA[1], false, false);
        u32x2 rC = __builtin_amdgcn_permlane32_swap(w23[2 * ks], w23[2 * ks + 1], false, false);
        u32x2 rD = __builtin_amdgcn_permlane16_swap(rC[0], rC[1], false, false);
        const u32x4 pd = (u32x4){rB[0], rD[0], rB[1], rD[1]};
        pa[qs][ks] = __builtin_bit_cast(s16x8, pd);
      }
    }

    __builtin_amdgcn_s_setprio(1);
#pragma unroll
    for (int ks = 0; ks < 2; ++ks) {
#pragma unroll
      for (int d = 0; d < 4; ++d) {
        const int rowv = d * 16 + m15;
        const s16x8 bv = *(const s16x8*)&VTc[(rowv * 8 + ((ks * 4 + g) ^ (rowv & 7))) * 8];
        o[0][d] = MFMA16(pa[0][ks], bv, o[0][d]);
        o[1][d] = MFMA16(pa[1][ks], bv, o[1][d]);
      }
      ls4[0] = MFMA16(pa[0][ks], vone, ls4[0]);
      ls4[1] = MFMA16(pa[1][ks], vone, ls4[1]);
    }
    __builtin_amdgcn_s_setprio(0);
    cur ^= 1;
  }
#undef STAGE

#pragma unroll
  for (int qs = 0; qs < 2; ++qs) {
    const int orow = b * 2048 + qw + qs * 16 + g * 4;
    const int ocol = h * 64 + m15;
#pragma unroll
    for (int r = 0; r < 4; ++r) {
#pragma unroll
      for (int d = 0; d < 4; ++d)
        poh[(orow + r) * 1024 + ocol + d * 16] = f2bf(o[qs][d][r]);
      if (m15 == 0) plsh[(orow + r) * 16 + h] = ls4[qs][r];
    }
  }
}

// ---------------- launch ----------------

extern "C" void kernel_launch(void* const* d_in, const int* in_sizes, int n_in,
                              void* d_out, int out_size, void* d_ws, size_t ws_size,
                              hipStream_t stream) {
  (void)in_sizes; (void)n_in; (void)out_size; (void)ws_size;
  const float* hs  = (const float*)d_in[0];
  const float* Wq  = (const float*)d_in[1];
  const float* Wk  = (const float*)d_in[2];
  const float* Wv  = (const float*)d_in[3];
  const float* Wo  = (const float*)d_in[4];
  const float* tbl = (const float*)d_in[5];

  char* ws = (char*)d_ws;
  u16* hsb   = (u16*)(ws);                 // 8 MB  bf16 hidden (dead after gemm_qkv -> po1)
  u16* wt    = (u16*)(ws + 8388608);       // 6 MB  W^T bf16 (dead after gemm_qkv -> pls)
  u16* wot   = (u16*)(ws + 14680064);      // 2 MB  Wo^T bf16
  u16* q     = (u16*)(ws + 16777216);      // 8 MB  Q bf16 (scaled)
  u16* k     = (u16*)(ws + 25165824);      // 8 MB  K bf16
  u16* po0   = (u16*)(ws + 33554432);      // 8 MB  partial numerator half 0
  u16* vt    = (u16*)(ws + 41943040);      // 8 MB  V^T bf16 [32][64][2048]
  float* biasT = (float*)(ws + 58720256);  // 256 KB bias table [16][4096]
  u16* po1   = hsb;                        // partial 1 aliases hsb (dead by then)
  float* pls = (float*)wt;                 // aliases wt (dead by then)

  prep<<<4352, 256, 0, stream>>>(hs, Wq, Wk, Wv, Wo, tbl, hsb, wt, wot, biasT);
  gemm_qkv<<<768, 256, 0, stream>>>(hsb, wt, q, k, vt);
  attn_kernel<<<1024, 256, 0, stream>>>(q, k, vt, biasT, tbl, po0, po1, pls);
  gemm_out<<<512, 256, 0, stream>>>(po0, po1, pls, wot, (float*)d_out);
}

// Round 12
// 117.205 us; speedup vs baseline: 1.0790x; 1.0790x over previous
//
#include <hip/hip_runtime.h>

typedef __attribute__((ext_vector_type(8))) short s16x8;
typedef __attribute__((ext_vector_type(4))) short s16x4;
typedef __attribute__((ext_vector_type(4))) float f32x4;
typedef __attribute__((ext_vector_type(4))) unsigned int u32x4;
typedef __attribute__((ext_vector_type(2))) unsigned int u32x2;
typedef unsigned short u16;
typedef unsigned int u32;

#define LOG2E 1.4426950408889634f

__device__ __forceinline__ u16 f2bf(float x) {
  u32 u = __float_as_uint(x);
  u += 0x7FFFu + ((u >> 16) & 1u);
  return (u16)(u >> 16);
}

__device__ __forceinline__ float bf2f(u16 x) {
  return __uint_as_float((u32)x << 16);
}

// pack two f32 into bf16x2 (truncating) with a single v_perm_b32
__device__ __forceinline__ u32 pack_bf_trunc(float lo, float hi) {
  return __builtin_amdgcn_perm(__float_as_uint(hi), __float_as_uint(lo), 0x07060302u);
}

__device__ __forceinline__ void gl_lds16(const void* g, void* l) {
  __builtin_amdgcn_global_load_lds((const __attribute__((address_space(1))) void*)g,
                                   (__attribute__((address_space(3))) void*)l, 16, 0, 0);
}

#define MFMA16(a, b, c) __builtin_amdgcn_mfma_f32_16x16x32_bf16((a), (b), (c), 0, 0, 0)

// ---------------- fused prep kernel ----------------

__global__ __launch_bounds__(256) void prep(const float* __restrict__ hs,
                                            const float* __restrict__ Wq,
                                            const float* __restrict__ Wk,
                                            const float* __restrict__ Wv,
                                            const float* __restrict__ Wo,
                                            const float* __restrict__ tbl,
                                            u16* __restrict__ hsb,
                                            u16* __restrict__ wt,
                                            u16* __restrict__ wot,
                                            float* __restrict__ biasT) {
  const int blk = blockIdx.x;
  const int tid = threadIdx.x;
  if (blk < 2048) {
    const int i = blk * 256 + tid;
    const float4* s4 = (const float4*)hs;
    float4 a = s4[i * 2];
    float4 b = s4[i * 2 + 1];
    s16x8 o;
    o[0] = (short)f2bf(a.x); o[1] = (short)f2bf(a.y);
    o[2] = (short)f2bf(a.z); o[3] = (short)f2bf(a.w);
    o[4] = (short)f2bf(b.x); o[5] = (short)f2bf(b.y);
    o[6] = (short)f2bf(b.z); o[7] = (short)f2bf(b.w);
    *(s16x8*)&hsb[i * 8] = o;
  } else if (blk < 4096) {
    int r = blk - 2048;
    const int sel = r >> 9;
    r &= 511;
    const float* W = sel == 0 ? Wq : (sel == 1 ? Wk : (sel == 2 ? Wv : Wo));
    u16* dst = sel == 3 ? wot : wt + sel * 1048576;
    const int n = (r & 15) * 64 + (tid & 63);
    const int kb = (r >> 4) * 32 + (tid >> 6) * 8;
    s16x8 o;
#pragma unroll
    for (int j = 0; j < 8; ++j) o[j] = (short)f2bf(W[(kb + j) * 1024 + n]);
    *(s16x8*)&dst[n * 1024 + kb] = o;
  } else {
    const int i = (blk - 4096) * 256 + tid;
    const int h = i >> 12, dp = i & 4095;
    const int delta = dp - 2047;
    const int rp = delta < 0 ? -delta : delta;
    int bucket = delta > 0 ? 16 : 0;
    if (rp < 8)
      bucket += rp;
    else
      bucket += 8 + (rp >= 12) + (rp >= 16) + (rp >= 23) + (rp >= 32) +
                (rp >= 46) + (rp >= 64) + (rp >= 91);
    biasT[i] = tbl[bucket * 16 + h] * LOG2E;
  }
}

// ---------------- GEMM core v2: 2-phase double-buffered, 128x128 ----------------

__device__ __forceinline__ void gemm_core(const u16* __restrict__ A,
                                          const u16* __restrict__ Bt,
                                          int m0, int n0,
                                          u16* shbuf, f32x4 acc[4][4]) {
  const int tid = threadIdx.x;
  const int w = tid >> 6, l = tid & 63, g = l >> 4, m15 = l & 15;
  const int wr = (w >> 1) * 64, wc = (w & 1) * 64;
#pragma unroll
  for (int i = 0; i < 4; ++i)
#pragma unroll
    for (int j = 0; j < 4; ++j) acc[i][j] = (f32x4){0.f, 0.f, 0.f, 0.f};

#define GSTAGE(buf, k0)                                                    \
  {                                                                        \
    _Pragma("unroll") for (int c = 0; c < 2; ++c) {                        \
      const int idx = c * 256 + tid;                                       \
      const int row = idx >> 2, col4 = idx & 3;                            \
      const int scol = col4 ^ ((row >> 1) & 3);                            \
      gl_lds16(&A[(m0 + row) * 1024 + (k0) + scol * 8],                    \
               (char*)shbuf + (buf)*8192 + c * 4096 + w * 1024);           \
      gl_lds16(&Bt[(n0 + row) * 1024 + (k0) + scol * 8],                   \
               (char*)shbuf + 16384 + (buf)*8192 + c * 4096 + w * 1024);   \
    }                                                                      \
  }

  GSTAGE(0, 0);
  int cur = 0;
  for (int kt = 0; kt < 32; ++kt) {
    __syncthreads();  // drains vmcnt: buf[cur] ready; buf[cur^1] reads done
    if (kt < 31) GSTAGE(cur ^ 1, (kt + 1) * 32);
    const u16* Asb = shbuf + cur * 4096;
    const u16* Bsb = shbuf + 8192 + cur * 4096;
    s16x8 af[4], bfr[4];
#pragma unroll
    for (int mf = 0; mf < 4; ++mf) {
      const int row = wr + mf * 16 + m15;
      af[mf] = *(const s16x8*)&Asb[(row * 4 + (g ^ ((row >> 1) & 3))) * 8];
    }
#pragma unroll
    for (int nf = 0; nf < 4; ++nf) {
      const int row = wc + nf * 16 + m15;
      bfr[nf] = *(const s16x8*)&Bsb[(row * 4 + (g ^ ((row >> 1) & 3))) * 8];
    }
#pragma unroll
    for (int mf = 0; mf < 4; ++mf)
#pragma unroll
      for (int nf = 0; nf < 4; ++nf)
        acc[mf][nf] = MFMA16(af[mf], bfr[nf], acc[mf][nf]);
    cur ^= 1;
  }
#undef GSTAGE
}

// QKV: grid 768 blocks 1D, XCD-chunked (8m x 12n per XCD).
// Q/K row-major [4096][1024]; V transposed through LDS (coalesced) to
// VT[(b*16+h)*64 + d][2048].
__global__ __launch_bounds__(256) void gemm_qkv(const u16* __restrict__ X,
                                                const u16* __restrict__ Wt,
                                                u16* __restrict__ Q,
                                                u16* __restrict__ Kb,
                                                u16* __restrict__ VT) {
  __shared__ u16 shbuf[16384];  // 32 KB: dbuf A|B during GEMM, transpose tile after
  f32x4 acc[4][4];
  const int flat = blockIdx.x;
  const int x = flat & 7, i = flat >> 3;  // i in [0,96)
  const int m0 = ((x & 3) * 8 + (i & 7)) * 128;
  const int n0 = ((x >> 2) * 12 + (i >> 3)) * 128;
  gemm_core(X, Wt, m0, n0, shbuf, acc);

  const int tid = threadIdx.x;
  const int w = tid >> 6, l = tid & 63, g = l >> 4, m15 = l & 15;
  const int wr = (w >> 1) * 64, wc = (w & 1) * 64;
  const int nsel = n0 >> 10;
  const int ncol0 = (n0 & 1023) + wc;
  if (nsel == 2) {
    // V^T via LDS transpose then coalesced 16B stores along s.
    __syncthreads();
#pragma unroll
    for (int mf = 0; mf < 4; ++mf) {
      const int s_base = wr + mf * 16 + g * 4;
#pragma unroll
      for (int nf = 0; nf < 4; ++nf) {
        const int d_loc = wc + nf * 16 + m15;
        s16x4 pk;
#pragma unroll
        for (int r = 0; r < 4; ++r) pk[r] = (short)f2bf(acc[mf][nf][r]);
        *(s16x4*)&shbuf[d_loc * 128 + (s_base ^ ((d_loc & 7) << 3))] = pk;
      }
    }
    __syncthreads();
    const int b = m0 >> 11, sg0 = m0 & 2047;
#pragma unroll
    for (int it = 0; it < 8; ++it) {
      const int d_loc = it * 16 + w * 4 + g;
      const s16x8 v =
          *(const s16x8*)&shbuf[d_loc * 128 + ((m15 * 8) ^ ((d_loc & 7) << 3))];
      const int col = (n0 & 1023) + d_loc;
      *(s16x8*)&VT[((b * 16 + (col >> 6)) * 64 + (col & 63)) * 2048 + sg0 + m15 * 8] = v;
    }
  } else {
    u16* dst = nsel == 0 ? Q : Kb;
    const float scale = nsel == 0 ? 0.125f * LOG2E : 1.0f;
#pragma unroll
    for (int mf = 0; mf < 4; ++mf) {
      const int rbase = m0 + wr + mf * 16 + g * 4;
#pragma unroll
      for (int nf = 0; nf < 4; ++nf) {
        const int col = ncol0 + nf * 16 + m15;
#pragma unroll
        for (int r = 0; r < 4; ++r)
          dst[(rbase + r) * 1024 + col] = f2bf(acc[mf][nf][r] * scale);
      }
    }
  }
}

// ---------------- gemm_out: 128x64 tiles, 512 blocks (2/CU) ----------------
// Same 2-phase pipeline, B-panel is 64 rows (4KB/buf). LDS 24KB.

__global__ __launch_bounds__(256) void gemm_out(const u16* __restrict__ CTX,
                                                const u16* __restrict__ Wot,
                                                float* __restrict__ Out) {
  __shared__ u16 shbuf[12288];  // A dbuf 16KB | B dbuf 8KB
  f32x4 acc[4][2];
  const int flat = blockIdx.x;
  const int x = flat & 7, i = flat >> 3;  // i in [0,64)
  const int m0 = ((x & 3) * 8 + (i & 7)) * 128;
  const int n0 = ((x >> 2) * 8 + (i >> 3)) * 64;

  const int tid = threadIdx.x;
  const int w = tid >> 6, l = tid & 63, g = l >> 4, m15 = l & 15;
  const int wr = (w >> 1) * 64, wc = (w & 1) * 32;
#pragma unroll
  for (int mf = 0; mf < 4; ++mf)
#pragma unroll
    for (int nf = 0; nf < 2; ++nf) acc[mf][nf] = (f32x4){0.f, 0.f, 0.f, 0.f};

#define OSTAGE(buf, k0)                                                    \
  {                                                                        \
    _Pragma("unroll") for (int c = 0; c < 2; ++c) {                        \
      const int idx = c * 256 + tid;                                       \
      const int row = idx >> 2, col4 = idx & 3;                            \
      const int scol = col4 ^ ((row >> 1) & 3);                            \
      gl_lds16(&CTX[(m0 + row) * 1024 + (k0) + scol * 8],                  \
               (char*)shbuf + (buf)*8192 + c * 4096 + w * 1024);           \
    }                                                                      \
    {                                                                      \
      const int row = tid >> 2, col4 = tid & 3;                            \
      const int scol = col4 ^ ((row >> 1) & 3);                            \
      gl_lds16(&Wot[(n0 + row) * 1024 + (k0) + scol * 8],                  \
               (char*)shbuf + 16384 + (buf)*4096 + (w >> 1) * 2048 +       \
                   (tid & 127) * 16);                                      \
    }                                                                      \
  }

  OSTAGE(0, 0);
  int cur = 0;
  for (int kt = 0; kt < 32; ++kt) {
    __syncthreads();
    if (kt < 31) OSTAGE(cur ^ 1, (kt + 1) * 32);
    const u16* Asb = shbuf + cur * 4096;
    const u16* Bsb = shbuf + 8192 + cur * 2048;
    s16x8 af[4], bfr[2];
#pragma unroll
    for (int mf = 0; mf < 4; ++mf) {
      const int row = wr + mf * 16 + m15;
      af[mf] = *(const s16x8*)&Asb[(row * 4 + (g ^ ((row >> 1) & 3))) * 8];
    }
#pragma unroll
    for (int nf = 0; nf < 2; ++nf) {
      const int row = wc + nf * 16 + m15;
      bfr[nf] = *(const s16x8*)&Bsb[(row * 4 + (g ^ ((row >> 1) & 3))) * 8];
    }
#pragma unroll
    for (int mf = 0; mf < 4; ++mf)
#pragma unroll
      for (int nf = 0; nf < 2; ++nf)
        acc[mf][nf] = MFMA16(af[mf], bfr[nf], acc[mf][nf]);
    cur ^= 1;
  }
#undef OSTAGE

#pragma unroll
  for (int mf = 0; mf < 4; ++mf) {
    const int rbase = m0 + wr + mf * 16 + g * 4;
#pragma unroll
    for (int nf = 0; nf < 2; ++nf) {
      const int col = n0 + wc + nf * 16 + m15;
#pragma unroll
      for (int r = 0; r < 4; ++r)
        Out[(rbase + r) * 1024 + col] = acc[mf][nf][r];
    }
  }
}

// ---------------- flash attention v5: KV-split x2 (proven config) ----------------
// 1 block = (b, h, 128 q-rows, kv half of 1024); 4 waves x 32 q-rows.
// Grid 1024. No-max exp2 softmax: out = (o0+o1)/(ls0+ls1) exact.
// Swapped QK^T + in-register permlane redistribution (no P LDS).

__global__ __launch_bounds__(256, 4) void attn_kernel(const u16* __restrict__ Qg,
                                                      const u16* __restrict__ Kg,
                                                      const u16* __restrict__ VTg,
                                                      const float* __restrict__ biasT,
                                                      const float* __restrict__ tbl,
                                                      u16* __restrict__ po0,
                                                      u16* __restrict__ po1,
                                                      float* __restrict__ pls) {
  __shared__ u16 KT[2][4096];   // [64 kv][64 kdim] swizzled, dbuf
  __shared__ u16 VTs[2][4096];  // [64 dv][64 kv]  swizzled, dbuf

  const int tid = threadIdx.x;
  const int w = tid >> 6, l = tid & 63, g = l >> 4, m15 = l & 15;
  const int flat = blockIdx.x;
  const int nf_ = (flat & 7) * 128 + (flat >> 3);
  const int bh = nf_ >> 5;
  const int rem = nf_ & 31;
  const int half = rem >> 4, qblk = rem & 15;
  const int b = bh >> 4, h = bh & 15;
  const int qw = qblk * 128 + w * 32;  // this wave's q base (32 rows)
  const int kvbase = half * 1024;

  u16* poh = half ? po1 : po0;
  float* plsh = pls + half * 65536;

  const float fpos = tbl[31 * 16 + h] * LOG2E;  // delta >= 91 bucket
  const float fneg = tbl[15 * 16 + h] * LOG2E;  // delta <= -91 bucket

  s16x8 aq[2][2];
#pragma unroll
  for (int qs = 0; qs < 2; ++qs) {
    const u16* qp = &Qg[(b * 2048 + qw + qs * 16 + m15) * 1024 + h * 64 + g * 8];
    aq[qs][0] = *(const s16x8*)qp;
    aq[qs][1] = *(const s16x8*)(qp + 32);
  }

  s16x8 vone;
#pragma unroll
  for (int j = 0; j < 8; ++j) vone[j] = (short)0x3F80;  // bf16 1.0

  f32x4 o[2][4];
  f32x4 ls4[2];
#pragma unroll
  for (int qs = 0; qs < 2; ++qs) {
    ls4[qs] = (f32x4){0.f, 0.f, 0.f, 0.f};
#pragma unroll
    for (int d = 0; d < 4; ++d) o[qs][d] = (f32x4){0.f, 0.f, 0.f, 0.f};
  }

  const u16* Kbase = &Kg[(b * 2048 + kvbase) * 1024 + h * 64];
  const u16* Vbase = &VTg[bh * 64 * 2048 + kvbase];

#define STAGE(buf, kv0)                                                          \
  {                                                                              \
    _Pragma("unroll") for (int c = 0; c < 2; ++c) {                              \
      const int idx = c * 256 + tid;                                             \
      const int row = idx >> 3, col16 = idx & 7;                                 \
      const int scol = col16 ^ (row & 7);                                        \
      gl_lds16(&Kbase[(kv0 + row) * 1024 + scol * 8],                            \
               (char*)KT + (buf)*8192 + c * 4096 + w * 1024);                    \
      gl_lds16(&Vbase[row * 2048 + (kv0) + scol * 8],                            \
               (char*)VTs + (buf)*8192 + c * 4096 + w * 1024);                   \
    }                                                                            \
  }

  STAGE(0, 0);
  int cur = 0;
  for (int t = 0; t < 16; ++t) {
    const int kv0 = t * 64;  // relative to kvbase
    __syncthreads();         // drains vmcnt: buf[cur] ready; buf[cur^1] free
    if (t < 15) STAGE(cur ^ 1, kv0 + 64);

    const u16* KTc = &KT[cur][0];
    const u16* VTc = &VTs[cur][0];

    f32x4 s[2][4];
    const int diff = kvbase + kv0 - qw;
    if (diff <= -160 || diff >= 128) {
      const float bc = diff > 0 ? fpos : fneg;
#pragma unroll
      for (int qs = 0; qs < 2; ++qs)
#pragma unroll
        for (int c = 0; c < 4; ++c) s[qs][c] = (f32x4){bc, bc, bc, bc};
    } else {
#pragma unroll
      for (int qs = 0; qs < 2; ++qs) {
        const float* bp =
            &biasT[h * 4096 + kvbase + kv0 + g * 4 - qw - qs * 16 - m15 + 2047];
#pragma unroll
        for (int c = 0; c < 4; ++c)
#pragma unroll
          for (int r = 0; r < 4; ++r) s[qs][c][r] = bp[c * 16 + r];
      }
    }

    __builtin_amdgcn_s_setprio(1);
#pragma unroll
    for (int ks = 0; ks < 2; ++ks) {
#pragma unroll
      for (int c = 0; c < 4; ++c) {
        const int row = c * 16 + m15;
        const s16x8 bk = *(const s16x8*)&KTc[(row * 8 + ((ks * 4 + g) ^ (row & 7))) * 8];
        s[0][c] = MFMA16(bk, aq[0][ks], s[0][c]);
        s[1][c] = MFMA16(bk, aq[1][ks], s[1][c]);
      }
    }
    __builtin_amdgcn_s_setprio(0);

    s16x8 pa[2][2];
#pragma unroll
    for (int qs = 0; qs < 2; ++qs) {
      u32 w01[4], w23[4];
#pragma unroll
      for (int c = 0; c < 4; ++c) {
        w01[c] = pack_bf_trunc(__builtin_amdgcn_exp2f(s[qs][c][0]),
                               __builtin_amdgcn_exp2f(s[qs][c][1]));
        w23[c] = pack_bf_trunc(__builtin_amdgcn_exp2f(s[qs][c][2]),
                               __builtin_amdgcn_exp2f(s[qs][c][3]));
      }
#pragma unroll
      for (int ks = 0; ks < 2; ++ks) {
        u32x2 rA = __builtin_amdgcn_permlane32_swap(w01[2 * ks], w01[2 * ks + 1], false, false);
        u32x2 rB = __builtin_amdgcn_permlane16_swap(rA[0], rA[1], false, false);
        u32x2 rC = __builtin_amdgcn_permlane32_swap(w23[2 * ks], w23[2 * ks + 1], false, false);
        u32x2 rD = __builtin_amdgcn_permlane16_swap(rC[0], rC[1], false, false);
        const u32x4 pd = (u32x4){rB[0], rD[0], rB[1], rD[1]};
        pa[qs][ks] = __builtin_bit_cast(s16x8, pd);
      }
    }

    __builtin_amdgcn_s_setprio(1);
#pragma unroll
    for (int ks = 0; ks < 2; ++ks) {
#pragma unroll
      for (int d = 0; d < 4; ++d) {
        const int rowv = d * 16 + m15;
        const s16x8 bv = *(const s16x8*)&VTc[(rowv * 8 + ((ks * 4 + g) ^ (rowv & 7))) * 8];
        o[0][d] = MFMA16(pa[0][ks], bv, o[0][d]);
        o[1][d] = MFMA16(pa[1][ks], bv, o[1][d]);
      }
      ls4[0] = MFMA16(pa[0][ks], vone, ls4[0]);
      ls4[1] = MFMA16(pa[1][ks], vone, ls4[1]);
    }
    __builtin_amdgcn_s_setprio(0);
    cur ^= 1;
  }
#undef STAGE

#pragma unroll
  for (int qs = 0; qs < 2; ++qs) {
    const int orow = b * 2048 + qw + qs * 16 + g * 4;
    const int ocol = h * 64 + m15;
#pragma unroll
    for (int r = 0; r < 4; ++r) {
#pragma unroll
      for (int d = 0; d < 4; ++d)
        poh[(orow + r) * 1024 + ocol + d * 16] = f2bf(o[qs][d][r]);
      if (m15 == 0) plsh[(orow + r) * 16 + h] = ls4[qs][r];
    }
  }
}

// ---------------- merge: ctx = (o0+o1)/(ls0+ls1) ----------------
__global__ __launch_bounds__(256) void merge(const u16* __restrict__ po0,
                                             const u16* __restrict__ po1,
                                             const float* __restrict__ pls,
                                             u16* __restrict__ ctx) {
  const int i = blockIdx.x * 256 + threadIdx.x;  // 524288
  const int row = i >> 7;
  const int seg = i & 127;
  const int h = seg >> 3;
  const float den = 1.0f / (pls[row * 16 + h] + pls[65536 + row * 16 + h]);
  const s16x8 a = *(const s16x8*)&po0[row * 1024 + seg * 8];
  const s16x8 b = *(const s16x8*)&po1[row * 1024 + seg * 8];
  s16x8 o;
#pragma unroll
  for (int j = 0; j < 8; ++j)
    o[j] = (short)f2bf((bf2f((u16)a[j]) + bf2f((u16)b[j])) * den);
  *(s16x8*)&ctx[row * 1024 + seg * 8] = o;
}

// ---------------- launch ----------------

extern "C" void kernel_launch(void* const* d_in, const int* in_sizes, int n_in,
                              void* d_out, int out_size, void* d_ws, size_t ws_size,
                              hipStream_t stream) {
  (void)in_sizes; (void)n_in; (void)out_size; (void)ws_size;
  const float* hs  = (const float*)d_in[0];
  const float* Wq  = (const float*)d_in[1];
  const float* Wk  = (const float*)d_in[2];
  const float* Wv  = (const float*)d_in[3];
  const float* Wo  = (const float*)d_in[4];
  const float* tbl = (const float*)d_in[5];

  char* ws = (char*)d_ws;
  u16* hsb   = (u16*)(ws);                 // 8 MB  bf16 hidden (dead after gemm_qkv -> po1)
  u16* wt    = (u16*)(ws + 8388608);       // 6 MB  W^T bf16 (dead after gemm_qkv -> pls)
  u16* wot   = (u16*)(ws + 14680064);      // 2 MB  Wo^T bf16
  u16* q     = (u16*)(ws + 16777216);      // 8 MB  Q bf16 (scaled)
  u16* k     = (u16*)(ws + 25165824);      // 8 MB  K bf16
  u16* po0   = (u16*)(ws + 33554432);      // 8 MB  partial numerator half 0
  u16* vt    = (u16*)(ws + 41943040);      // 8 MB  V^T bf16 [32][64][2048]
  u16* ctx   = (u16*)(ws + 50331648);      // 8 MB  merged attn output bf16
  float* biasT = (float*)(ws + 58720256);  // 256 KB bias table [16][4096]
  u16* po1   = hsb;                        // partial 1 aliases hsb (dead by then)
  float* pls = (float*)wt;                 // aliases wt (dead by then)

  prep<<<4352, 256, 0, stream>>>(hs, Wq, Wk, Wv, Wo, tbl, hsb, wt, wot, biasT);
  gemm_qkv<<<768, 256, 0, stream>>>(hsb, wt, q, k, vt);
  attn_kernel<<<1024, 256, 0, stream>>>(q, k, vt, biasT, tbl, po0, po1, pls);
  merge<<<2048, 256, 0, stream>>>(po0, po1, pls, ctx);
  gemm_out<<<512, 256, 0, stream>>>(ctx, wot, (float*)d_out);
}